// Round 1
// baseline (5379.845 us; speedup 1.0000x reference)
//
#include <hip/hip_runtime.h>
#include <cstdint>
#include <cstddef>

// Problem constants (from reference)
#define BSZ    32
#define SEQL   2048
#define ENCD   512
#define DE     1024   // DEC + ENC
#define NHEADS 8
#define IHD    1024   // INTERM * HEADS
#define TM     16     // seq rows per block in main kernel

__device__ __forceinline__ float softplus_f(float x) {
    // numerically stable: max(x,0) + log1p(exp(-|x|))  == jax.nn.softplus
    return fmaxf(x, 0.0f) + log1pf(expf(-fabsf(x)));
}

// ---------------------------------------------------------------------------
// Kernel 1: per-batch prep.
//   query[b,:]  = dec[b,:] @ Wq + bq                      (IH)
//   beta[b,h]   = softplus(dec[b,:] @ Wb + bb)            (HEADS)
//   kappa[b,h]  = kappa_in[b,h] + softplus(dec@Wk + bk)   (HEADS) -> d_out
// ---------------------------------------------------------------------------
__global__ __launch_bounds__(256) void prep_kernel(
    const float* __restrict__ dec, const float* __restrict__ kappa_in,
    const float* __restrict__ Wq, const float* __restrict__ bq,
    const float* __restrict__ Wb, const float* __restrict__ bb,
    const float* __restrict__ Wk, const float* __restrict__ bk,
    float* __restrict__ query_ws, float* __restrict__ beta_ws,
    float* __restrict__ kappa_out)
{
    __shared__ float s_dec[DE];
    const int b = blockIdx.x, tid = threadIdx.x;
    for (int i = tid; i < DE; i += 256) s_dec[i] = dec[b * DE + i];
    __syncthreads();

    // query: each thread computes 4 strided outputs (coalesced Wq reads)
    float a0 = bq[tid], a1 = bq[tid + 256], a2 = bq[tid + 512], a3 = bq[tid + 768];
    for (int k = 0; k < DE; ++k) {
        const float d = s_dec[k];
        const float* w = Wq + (size_t)k * IHD + tid;
        a0 = fmaf(d, w[0],   a0);
        a1 = fmaf(d, w[256], a1);
        a2 = fmaf(d, w[512], a2);
        a3 = fmaf(d, w[768], a3);
    }
    query_ws[b * IHD + tid]       = a0;
    query_ws[b * IHD + tid + 256] = a1;
    query_ws[b * IHD + tid + 512] = a2;
    query_ws[b * IHD + tid + 768] = a3;

    if (tid < NHEADS) {
        float ab = bb[tid], ak = bk[tid];
        for (int k = 0; k < DE; ++k) {
            const float d = s_dec[k];
            ab = fmaf(d, Wb[k * NHEADS + tid], ab);
            ak = fmaf(d, Wk[k * NHEADS + tid], ak);
        }
        beta_ws[b * NHEADS + tid]   = softplus_f(ab);
        kappa_out[b * NHEADS + tid] = kappa_in[b * NHEADS + tid] + softplus_f(ak);
    }
}

// ---------------------------------------------------------------------------
// Kernel 2 (dominant): fused  value = enc@Wv+bv ;
//   alpha = softplus(tanh(query+value) @ Wf + bf) * mask ;
//   score = alpha * exp(-beta*(kappa-u)^2)  -> d_out score section.
// Block: TM=16 seq rows x full IH, 256 threads as (r=tid>>4, c=tid&15).
// value row is chunked over N (16 chunks of 64 cols, 4 cols/thread as float4)
// and never materialized; per-head partial dots kept in registers, reduced
// across the 16 c-lanes with in-wave shuffles.
// ---------------------------------------------------------------------------
__global__ __launch_bounds__(256) void main_kernel(
    const float* __restrict__ enc, const float* __restrict__ mask,
    const float* __restrict__ Wv, const float* __restrict__ bv,
    const float* __restrict__ Wf, const float* __restrict__ bf,
    const float* __restrict__ query_ws, const float* __restrict__ beta_ws,
    const float* __restrict__ kappa_out, float* __restrict__ score_out)
{
    __shared__ float s_enc[TM][ENCD + 1];   // +1 pad: break 32-bank stride
    __shared__ float s_q[IHD];
    __shared__ float s_WfT[NHEADS][IHD];    // transposed: bank-friendly reads

    const int b  = blockIdx.y;
    const int s0 = blockIdx.x * TM;
    const int tid = threadIdx.x;

    for (int i = tid; i < IHD; i += 256) s_q[i] = query_ws[b * IHD + i];
    for (int i = tid; i < IHD * NHEADS; i += 256) {
        const int n = i >> 3, h = i & 7;
        s_WfT[h][n] = Wf[i];
    }
    const float* encB = enc + ((size_t)b * SEQL + s0) * ENCD;
    for (int i = tid; i < TM * ENCD; i += 256)
        s_enc[i / ENCD][i % ENCD] = encB[i];
    __syncthreads();

    const int r = tid >> 4;   // row 0..15
    const int c = tid & 15;   // col-group 0..15
    float ph[NHEADS] = {0, 0, 0, 0, 0, 0, 0, 0};

    for (int chunk = 0; chunk < 16; ++chunk) {
        const int n0 = chunk * 64 + c * 4;
        float4 a = *(const float4*)(bv + n0);
        const float* wp = Wv + n0;
        #pragma unroll 4
        for (int k = 0; k < ENCD; ++k) {
            const float e = s_enc[r][k];
            const float4 w = *(const float4*)(wp + (size_t)k * IHD);
            a.x = fmaf(e, w.x, a.x);
            a.y = fmaf(e, w.y, a.y);
            a.z = fmaf(e, w.z, a.z);
            a.w = fmaf(e, w.w, a.w);
        }
        const float t0 = tanhf(s_q[n0 + 0] + a.x);
        const float t1 = tanhf(s_q[n0 + 1] + a.y);
        const float t2 = tanhf(s_q[n0 + 2] + a.z);
        const float t3 = tanhf(s_q[n0 + 3] + a.w);
        #pragma unroll
        for (int h = 0; h < NHEADS; ++h) {
            ph[h] += t0 * s_WfT[h][n0 + 0] + t1 * s_WfT[h][n0 + 1]
                   + t2 * s_WfT[h][n0 + 2] + t3 * s_WfT[h][n0 + 3];
        }
    }

    // reduce over the 16 c-lanes (contiguous within a wave): xor butterfly
    #pragma unroll
    for (int m = 8; m >= 1; m >>= 1) {
        #pragma unroll
        for (int h = 0; h < NHEADS; ++h)
            ph[h] += __shfl_xor(ph[h], m, 64);
    }

    if (c < NHEADS) {
        // all 16 lanes hold all 8 head-sums; lane c takes head c
        float apre = ph[0];
        #pragma unroll
        for (int h = 1; h < NHEADS; ++h) apre = (c == h) ? ph[h] : apre;
        const int s = s0 + r;
        const float alpha = softplus_f(apre + bf[c]) * mask[b * SEQL + s];
        const float bet = beta_ws[b * NHEADS + c];
        const float kap = kappa_out[b * NHEADS + c];
        const float du  = kap - (float)s;
        score_out[((size_t)(b * SEQL + s)) * NHEADS + c] = alpha * expf(-bet * du * du);
    }
}

// ---------------------------------------------------------------------------
// Kernel 3: context[b,h,e] = sum_s score[b,s,h] * enc[b,s,e]
// grid (b, e-chunk of 256, s-chunk of 512); atomicAdd partials into ws.
// ---------------------------------------------------------------------------
__global__ __launch_bounds__(256) void context_kernel(
    const float* __restrict__ enc, const float* __restrict__ score,
    float* __restrict__ ctx_ws)
{
    __shared__ float s_sc[64][NHEADS];
    const int b   = blockIdx.x;
    const int ec  = blockIdx.y;
    const int scn = blockIdx.z;
    const int tid = threadIdx.x;
    const int e = ec * 256 + tid;
    float acc[NHEADS] = {0, 0, 0, 0, 0, 0, 0, 0};
    const int sbase = scn * 512;

    for (int tile = 0; tile < 8; ++tile) {
        const int st = sbase + tile * 64;
        __syncthreads();
        for (int i = tid; i < 64 * NHEADS; i += 256)
            ((float*)s_sc)[i] = score[((size_t)b * SEQL + st) * NHEADS + i];
        __syncthreads();
        const float* ep = enc + ((size_t)b * SEQL + st) * ENCD + e;
        for (int si = 0; si < 64; ++si) {
            const float ev = ep[(size_t)si * ENCD];
            #pragma unroll
            for (int h = 0; h < NHEADS; ++h)
                acc[h] = fmaf(s_sc[si][h], ev, acc[h]);
        }
    }
    #pragma unroll
    for (int h = 0; h < NHEADS; ++h)
        atomicAdd(&ctx_ws[(size_t)b * (NHEADS * ENCD) + h * ENCD + e], acc[h]);
}

// ---------------------------------------------------------------------------
// Kernel 4: out_ctx[b,:] = ctx[b,:] @ Wfc + bfc   (32 x 4096 @ 4096 x 512)
// grid (b, j-chunk of 128), 128 threads. 4 independent accumulators for ILP.
// ---------------------------------------------------------------------------
__global__ __launch_bounds__(128) void final_kernel(
    const float* __restrict__ ctx_ws,
    const float* __restrict__ Wfc, const float* __restrict__ bfc,
    float* __restrict__ out_ctx)
{
    __shared__ float s_ctx[NHEADS * ENCD];  // 4096
    const int b = blockIdx.x, jc = blockIdx.y, tid = threadIdx.x;
    for (int i = tid; i < NHEADS * ENCD; i += 128)
        s_ctx[i] = ctx_ws[(size_t)b * (NHEADS * ENCD) + i];
    __syncthreads();
    const int j = jc * 128 + tid;
    float a0 = 0.f, a1 = 0.f, a2 = 0.f, a3 = 0.f;
    for (int k = 0; k < NHEADS * ENCD; k += 4) {
        a0 = fmaf(s_ctx[k + 0], Wfc[(size_t)(k + 0) * ENCD + j], a0);
        a1 = fmaf(s_ctx[k + 1], Wfc[(size_t)(k + 1) * ENCD + j], a1);
        a2 = fmaf(s_ctx[k + 2], Wfc[(size_t)(k + 2) * ENCD + j], a2);
        a3 = fmaf(s_ctx[k + 3], Wfc[(size_t)(k + 3) * ENCD + j], a3);
    }
    out_ctx[b * ENCD + j] = ((a0 + a1) + (a2 + a3)) + bfc[j];
}

// ---------------------------------------------------------------------------
extern "C" void kernel_launch(void* const* d_in, const int* in_sizes, int n_in,
                              void* d_out, int out_size, void* d_ws, size_t ws_size,
                              hipStream_t stream)
{
    const float* enc   = (const float*)d_in[0];
    const float* dec   = (const float*)d_in[1];
    const float* kapin = (const float*)d_in[2];
    const float* mask  = (const float*)d_in[3];
    const float* Wv    = (const float*)d_in[4];
    const float* bv    = (const float*)d_in[5];
    const float* Wq    = (const float*)d_in[6];
    const float* bq    = (const float*)d_in[7];
    const float* Wf    = (const float*)d_in[8];
    const float* bf    = (const float*)d_in[9];
    const float* Wb    = (const float*)d_in[10];
    const float* bb    = (const float*)d_in[11];
    const float* Wk    = (const float*)d_in[12];
    const float* bk    = (const float*)d_in[13];
    const float* Wfc   = (const float*)d_in[14];
    const float* bfc   = (const float*)d_in[15];

    // Output layout (flat, return order): context(32*512) | kappa(32*8) | score(32*2048*8)
    float* out       = (float*)d_out;
    float* out_ctx   = out;                 // 16384 floats
    float* out_kappa = out + 16384;         // 256 floats
    float* out_score = out + 16640;         // 524288 floats

    // Workspace layout (floats): query(32768) | beta(256) | pad | ctx(131072)
    float* ws      = (float*)d_ws;
    float* q_ws    = ws;
    float* beta_ws = ws + 32768;
    float* ctx_ws  = ws + 33024;

    hipMemsetAsync(ctx_ws, 0, (size_t)BSZ * NHEADS * ENCD * sizeof(float), stream);

    prep_kernel<<<dim3(BSZ), dim3(256), 0, stream>>>(
        dec, kapin, Wq, bq, Wb, bb, Wk, bk, q_ws, beta_ws, out_kappa);

    main_kernel<<<dim3(SEQL / TM, BSZ), dim3(256), 0, stream>>>(
        enc, mask, Wv, bv, Wf, bf, q_ws, beta_ws, out_kappa, out_score);

    context_kernel<<<dim3(BSZ, 2, 4), dim3(256), 0, stream>>>(
        enc, out_score, ctx_ws);

    final_kernel<<<dim3(BSZ, 4), dim3(128), 0, stream>>>(
        ctx_ws, Wfc, bfc, out_ctx);
}

// Round 2
// 707.766 us; speedup vs baseline: 7.6012x; 7.6012x over previous
//
#include <hip/hip_runtime.h>
#include <cstdint>
#include <cstddef>

#define BSZ    32
#define SEQL   2048
#define ENCD   512
#define DE     1024   // DEC + ENC
#define NHEADS 8
#define IHD    1024   // INTERM * HEADS

typedef unsigned short u16;
typedef __bf16 bf16x8 __attribute__((ext_vector_type(8)));
typedef float floatx4 __attribute__((ext_vector_type(4)));
typedef unsigned short u16x8 __attribute__((ext_vector_type(8)));

__device__ __forceinline__ u16 f2bf(float f) {
    unsigned int u = __float_as_uint(f);
    u = (u + 0x7FFFu + ((u >> 16) & 1u)) >> 16;   // RNE
    return (u16)u;
}
__device__ __forceinline__ float bf2f(u16 v) {
    return __uint_as_float(((unsigned int)v) << 16);
}
__device__ __forceinline__ float softplus_f(float x) {
    return fmaxf(x, 0.0f) + log1pf(__expf(-fabsf(x)));
}
__device__ __forceinline__ float tanh_fast(float x) {
    const float e = __expf(2.0f * x);
    return 1.0f - 2.0f / (e + 1.0f);   // exact at +-inf, ~1e-7 rel otherwise
}
__device__ __forceinline__ void async_cp16(u16* lds, const u16* g) {
    __builtin_amdgcn_global_load_lds(
        (const __attribute__((address_space(1))) unsigned int*)g,
        (__attribute__((address_space(3))) unsigned int*)lds, 16, 0, 0);
}

// ---------------------------------------------------------------------------
// fp32 -> bf16 conversions
// ---------------------------------------------------------------------------
__global__ __launch_bounds__(256) void conv_enc_kernel(const float* __restrict__ in,
                                                       u16* __restrict__ out) {
    const size_t i = (size_t)blockIdx.x * 256 + threadIdx.x;   // group of 8
    const float4* p = (const float4*)in + i * 2;
    const float4 a = p[0], b = p[1];
    u16x8 o;
    o[0] = f2bf(a.x); o[1] = f2bf(a.y); o[2] = f2bf(a.z); o[3] = f2bf(a.w);
    o[4] = f2bf(b.x); o[5] = f2bf(b.y); o[6] = f2bf(b.z); o[7] = f2bf(b.w);
    *((u16x8*)out + i) = o;
}

// WvT[n][k] = bf16(Wv[k][n]);  Wv is (512 x 1024) row-major
__global__ __launch_bounds__(256) void conv_wvT_kernel(const float* __restrict__ Wv,
                                                       u16* __restrict__ WvT) {
    const int i = blockIdx.x * 256 + threadIdx.x;   // i = n*512 + k
    const int n = i >> 9, k = i & 511;
    WvT[i] = f2bf(Wv[(size_t)k * IHD + n]);
}

// ---------------------------------------------------------------------------
// prep: query = dec@Wq+bq ; beta = sp(dec@Wb+bb) ; kappa += sp(dec@Wk+bk)
// grid (BSZ, 4): block (b,q) computes query cols q*256..+255
// ---------------------------------------------------------------------------
__global__ __launch_bounds__(256) void prep_kernel(
    const float* __restrict__ dec, const float* __restrict__ kappa_in,
    const float* __restrict__ Wq, const float* __restrict__ bq,
    const float* __restrict__ Wb, const float* __restrict__ bb,
    const float* __restrict__ Wk, const float* __restrict__ bk,
    float* __restrict__ query_ws, float* __restrict__ beta_ws,
    float* __restrict__ kappa_out)
{
    __shared__ float s_dec[DE];
    const int b = blockIdx.x, q = blockIdx.y, tid = threadIdx.x;
    for (int i = tid; i < DE; i += 256) s_dec[i] = dec[b * DE + i];
    __syncthreads();

    const int col = q * 256 + tid;
    float a = bq[col];
    for (int k = 0; k < DE; ++k)
        a = fmaf(s_dec[k], Wq[(size_t)k * IHD + col], a);
    query_ws[b * IHD + col] = a;

    if (q == 0 && tid < NHEADS) {
        float ab = bb[tid], ak = bk[tid];
        for (int k = 0; k < DE; ++k) {
            const float d = s_dec[k];
            ab = fmaf(d, Wb[k * NHEADS + tid], ab);
            ak = fmaf(d, Wk[k * NHEADS + tid], ak);
        }
        beta_ws[b * NHEADS + tid]   = softplus_f(ab);
        kappa_out[b * NHEADS + tid] = kappa_in[b * NHEADS + tid] + softplus_f(ak);
    }
}

// ---------------------------------------------------------------------------
// Main: MFMA bf16 GEMM  value = enc @ Wv  (M=65536, N=IH=1024, K=512),
// fused epilogue: t = tanh(value + bv + query); pre_alpha[row][h] += t*Wf[n][h]
// 128x128 tile, 256 thr = 4 waves, each wave 64x64 (4x4 of 16x16x32 MFMA).
// ---------------------------------------------------------------------------
#define BM 128
#define BN 128
#define BK 32

__global__ __launch_bounds__(256) void gemm_alpha_kernel(
    const u16* __restrict__ encb, const u16* __restrict__ WvT,
    const float* __restrict__ bv, const float* __restrict__ Wf,
    const float* __restrict__ query_ws, float* __restrict__ pre_alpha)
{
    __shared__ __align__(16) u16 Abuf[BM * BK];       // [row][k], 64B rows
    __shared__ __align__(16) u16 Bbuf[BN * BK];       // [n][k]
    __shared__ __align__(16) float Wf_s[BN * NHEADS]; // Wf slice, row-major
    __shared__ float qb_s[BN];                        // query + bv slice

    const int tid = threadIdx.x;
    const int n0 = blockIdx.x * BN;
    const int m0 = blockIdx.y * BM;
    const int b  = m0 >> 11;                          // 2048 rows per batch

    for (int i = tid; i < BN * NHEADS; i += 256)
        Wf_s[i] = Wf[(size_t)n0 * NHEADS + i];
    if (tid < BN)
        qb_s[tid] = query_ws[(size_t)b * IHD + n0 + tid] + bv[n0 + tid];

    const int lane = tid & 63;
    const int w    = tid >> 6;
    const int wr   = w >> 1, wc = w & 1;

    // staging: wave w loads A rows [w*32, w*32+32) and B rows likewise;
    // per instr: 16 rows, lane -> row w*32+j*16+(lane>>2), k (lane&3)*8
    const int lrow = lane >> 2;
    const int lk   = (lane & 3) * 8;
    const u16* gA0 = encb + (size_t)(m0 + w * 32 + lrow) * 512 + lk;
    const u16* gA1 = gA0 + 16 * 512;
    const u16* gB0 = WvT + (size_t)(n0 + w * 32 + lrow) * 512 + lk;
    const u16* gB1 = gB0 + 16 * 512;
    u16* lA0 = &Abuf[(w * 32) * BK];
    u16* lA1 = &Abuf[(w * 32 + 16) * BK];
    u16* lB0 = &Bbuf[(w * 32) * BK];
    u16* lB1 = &Bbuf[(w * 32 + 16) * BK];

    floatx4 acc[4][4] = {};

    const int fr   = lane & 15;   // m (A) / n (B) index within 16-tile
    const int quad = lane >> 4;   // k-quad

    for (int kt = 0; kt < 512 / BK; ++kt) {
        const int ko = kt * BK;
        async_cp16(lA0, gA0 + ko);
        async_cp16(lA1, gA1 + ko);
        async_cp16(lB0, gB0 + ko);
        async_cp16(lB1, gB1 + ko);
        __syncthreads();   // drains vmcnt -> LDS ready

        bf16x8 af[4], bfr[4];
        #pragma unroll
        for (int t = 0; t < 4; ++t) {
            af[t]  = *(const bf16x8*)&Abuf[(wr * 64 + t * 16 + fr) * BK + quad * 8];
            bfr[t] = *(const bf16x8*)&Bbuf[(wc * 64 + t * 16 + fr) * BK + quad * 8];
        }
        #pragma unroll
        for (int mt = 0; mt < 4; ++mt)
            #pragma unroll
            for (int nt = 0; nt < 4; ++nt)
                acc[mt][nt] = __builtin_amdgcn_mfma_f32_16x16x32_bf16(
                    af[mt], bfr[nt], acc[mt][nt], 0, 0, 0);
        __syncthreads();   // protect LDS before next stage
    }

    // ---- fused epilogue: hoist Wf + q into registers, no LDS in hot loop
    float qv[4], wf[4][8];
    #pragma unroll
    for (int nt = 0; nt < 4; ++nt) {
        const int cl = wc * 64 + nt * 16 + fr;
        qv[nt] = qb_s[cl];
        const float4 w0 = *(const float4*)&Wf_s[cl * 8];
        const float4 w1 = *(const float4*)&Wf_s[cl * 8 + 4];
        wf[nt][0] = w0.x; wf[nt][1] = w0.y; wf[nt][2] = w0.z; wf[nt][3] = w0.w;
        wf[nt][4] = w1.x; wf[nt][5] = w1.y; wf[nt][6] = w1.z; wf[nt][7] = w1.w;
    }

    #pragma unroll
    for (int mt = 0; mt < 4; ++mt) {
        #pragma unroll
        for (int reg = 0; reg < 4; ++reg) {
            float ph[8] = {0, 0, 0, 0, 0, 0, 0, 0};
            #pragma unroll
            for (int nt = 0; nt < 4; ++nt) {
                const float t = tanh_fast(acc[mt][nt][reg] + qv[nt]);
                #pragma unroll
                for (int h = 0; h < 8; ++h)
                    ph[h] = fmaf(t, wf[nt][h], ph[h]);
            }
            // reduce over the 16 col-lanes (xor stays within 16-group)
            #pragma unroll
            for (int m = 8; m >= 1; m >>= 1)
                #pragma unroll
                for (int h = 0; h < 8; ++h)
                    ph[h] += __shfl_xor(ph[h], m, 64);
            if (fr < 8) {
                float val = ph[0];
                #pragma unroll
                for (int h = 1; h < 8; ++h) val = (fr == h) ? ph[h] : val;
                const int grow = m0 + wr * 64 + mt * 16 + quad * 4 + reg;
                atomicAdd(&pre_alpha[(size_t)grow * NHEADS + fr], val);
            }
        }
    }
}

// ---------------------------------------------------------------------------
// score = softplus(pre_alpha + bf) * mask * exp(-beta*(kappa-u)^2)
// ---------------------------------------------------------------------------
__global__ __launch_bounds__(256) void score_kernel(
    const float* __restrict__ pre_alpha, const float* __restrict__ bf,
    const float* __restrict__ mask, const float* __restrict__ beta_ws,
    const float* __restrict__ kappa_out, float* __restrict__ score_out)
{
    const int gid = blockIdx.x * 256 + threadIdx.x;   // < 65536*8
    const int h   = gid & 7;
    const int row = gid >> 3;
    const int b   = row >> 11;
    const int s   = row & 2047;
    const float alpha = softplus_f(pre_alpha[gid] + bf[h]) * mask[row];
    const float bet = beta_ws[b * NHEADS + h];
    const float kap = kappa_out[b * NHEADS + h];
    const float du  = kap - (float)s;
    score_out[gid] = alpha * __expf(-bet * du * du);
}

// ---------------------------------------------------------------------------
// context[b,h,e] = sum_s score[b,s,h] * enc[b,s,e]   (bf16 enc)
// grid (b, e-chunk of 256, s-chunk of 128)
// ---------------------------------------------------------------------------
__global__ __launch_bounds__(256) void context_kernel(
    const u16* __restrict__ encb, const float* __restrict__ score,
    float* __restrict__ ctx_ws)
{
    __shared__ float s_sc[64][NHEADS];
    const int b = blockIdx.x, ec = blockIdx.y, scn = blockIdx.z;
    const int tid = threadIdx.x;
    const int e = ec * 256 + tid;
    float acc[NHEADS] = {0, 0, 0, 0, 0, 0, 0, 0};

    for (int tile = 0; tile < 2; ++tile) {
        const int st = scn * 128 + tile * 64;
        __syncthreads();
        for (int i = tid; i < 64 * NHEADS; i += 256)
            ((float*)s_sc)[i] = score[((size_t)b * SEQL + st) * NHEADS + i];
        __syncthreads();
        const u16* ep = encb + ((size_t)b * SEQL + st) * ENCD + e;
        for (int si = 0; si < 64; ++si) {
            const float ev = bf2f(ep[(size_t)si * ENCD]);
            #pragma unroll
            for (int h = 0; h < NHEADS; ++h)
                acc[h] = fmaf(s_sc[si][h], ev, acc[h]);
        }
    }
    #pragma unroll
    for (int h = 0; h < NHEADS; ++h)
        atomicAdd(&ctx_ws[(size_t)b * (NHEADS * ENCD) + h * ENCD + e], acc[h]);
}

// ---------------------------------------------------------------------------
// out_ctx[b,j] = ctx[b,:] @ Wfc[:,j] + bfc[j]
// grid (jc=16, ks=8): block does 32 j-cols x all 32 b x 512 k; Wfc read once.
// ---------------------------------------------------------------------------
__global__ __launch_bounds__(256) void final_kernel(
    const float* __restrict__ ctx_ws, const float* __restrict__ Wfc,
    const float* __restrict__ bfc, float* __restrict__ out_ctx)
{
    __shared__ float s_ctx[32][128];
    const int jc = blockIdx.x, ks = blockIdx.y, tid = threadIdx.x;
    const int jl = tid & 31, bg = tid >> 5;           // bg 0..7 -> 4 b each
    const int j = jc * 32 + jl;
    float a0 = 0.f, a1 = 0.f, a2 = 0.f, a3 = 0.f;

    for (int t = 0; t < 4; ++t) {
        const int k0 = ks * 512 + t * 128;
        __syncthreads();
        for (int i = tid; i < 32 * 128; i += 256) {
            const int bb = i >> 7, kk = i & 127;
            s_ctx[bb][kk] = ctx_ws[(size_t)bb * (NHEADS * ENCD) + k0 + kk];
        }
        __syncthreads();
        for (int kk = 0; kk < 128; ++kk) {
            const float wv = Wfc[(size_t)(k0 + kk) * ENCD + j];
            a0 = fmaf(s_ctx[bg * 4 + 0][kk], wv, a0);
            a1 = fmaf(s_ctx[bg * 4 + 1][kk], wv, a1);
            a2 = fmaf(s_ctx[bg * 4 + 2][kk], wv, a2);
            a3 = fmaf(s_ctx[bg * 4 + 3][kk], wv, a3);
        }
    }
    const float bias = (ks == 0) ? bfc[j] : 0.0f;
    atomicAdd(&out_ctx[(bg * 4 + 0) * ENCD + j], a0 + bias);
    atomicAdd(&out_ctx[(bg * 4 + 1) * ENCD + j], a1 + bias);
    atomicAdd(&out_ctx[(bg * 4 + 2) * ENCD + j], a2 + bias);
    atomicAdd(&out_ctx[(bg * 4 + 3) * ENCD + j], a3 + bias);
}

// ---------------------------------------------------------------------------
extern "C" void kernel_launch(void* const* d_in, const int* in_sizes, int n_in,
                              void* d_out, int out_size, void* d_ws, size_t ws_size,
                              hipStream_t stream)
{
    const float* enc   = (const float*)d_in[0];
    const float* dec   = (const float*)d_in[1];
    const float* kapin = (const float*)d_in[2];
    const float* mask  = (const float*)d_in[3];
    const float* Wv    = (const float*)d_in[4];
    const float* bv    = (const float*)d_in[5];
    const float* Wq    = (const float*)d_in[6];
    const float* bq    = (const float*)d_in[7];
    const float* Wf    = (const float*)d_in[8];
    const float* bf    = (const float*)d_in[9];
    const float* Wb    = (const float*)d_in[10];
    const float* bb    = (const float*)d_in[11];
    const float* Wk    = (const float*)d_in[12];
    const float* bk    = (const float*)d_in[13];
    const float* Wfc   = (const float*)d_in[14];
    const float* bfc   = (const float*)d_in[15];

    // outputs: context(32*512) | kappa(32*8) | score(32*2048*8)
    float* out       = (float*)d_out;
    float* out_ctx   = out;
    float* out_kappa = out + 16384;
    float* out_score = out + 16640;

    // workspace layout (bytes)
    char* w = (char*)d_ws;
    u16*   enc_bf    = (u16*)w;                        // 67108864 B
    u16*   wvT       = (u16*)(w + 67108864);           //  1048576 B
    float* q_ws      = (float*)(w + 68157440);         //   131072 B
    float* beta_ws   = (float*)(w + 68288512);         //     1024 B
    float* pre_alpha = (float*)(w + 68289536);         //  2097152 B
    float* ctx_ws    = (float*)(w + 70386688);         //   524288 B

    hipMemsetAsync(pre_alpha, 0, 2097152, stream);
    hipMemsetAsync(ctx_ws, 0, 524288, stream);
    hipMemsetAsync(out_ctx, 0, 16384 * sizeof(float), stream);

    conv_enc_kernel<<<dim3(16384), dim3(256), 0, stream>>>(enc, enc_bf);
    conv_wvT_kernel<<<dim3(2048), dim3(256), 0, stream>>>(Wv, wvT);

    prep_kernel<<<dim3(BSZ, 4), dim3(256), 0, stream>>>(
        dec, kapin, Wq, bq, Wb, bb, Wk, bk, q_ws, beta_ws, out_kappa);

    gemm_alpha_kernel<<<dim3(IHD / BN, (BSZ * SEQL) / BM), dim3(256), 0, stream>>>(
        enc_bf, wvT, bv, Wf, q_ws, pre_alpha);

    score_kernel<<<dim3(2048), dim3(256), 0, stream>>>(
        pre_alpha, bf, mask, beta_ws, out_kappa, out_score);

    context_kernel<<<dim3(BSZ, 2, 16), dim3(256), 0, stream>>>(
        enc_bf, out_score, ctx_ws);

    final_kernel<<<dim3(16, 8), dim3(256), 0, stream>>>(
        ctx_ws, Wfc, bfc, out_ctx);
}

// Round 3
// 695.107 us; speedup vs baseline: 7.7396x; 1.0182x over previous
//
#include <hip/hip_runtime.h>
#include <cstdint>
#include <cstddef>

#define BSZ    32
#define SEQL   2048
#define ENCD   512
#define DE     1024   // DEC + ENC
#define NHEADS 8
#define IHD    1024   // INTERM * HEADS

typedef unsigned short u16;
typedef __bf16 bf16x8 __attribute__((ext_vector_type(8)));
typedef float floatx4 __attribute__((ext_vector_type(4)));
typedef unsigned short u16x8 __attribute__((ext_vector_type(8)));

__device__ __forceinline__ u16 f2bf(float f) {
    unsigned int u = __float_as_uint(f);
    u = (u + 0x7FFFu + ((u >> 16) & 1u)) >> 16;   // RNE
    return (u16)u;
}
__device__ __forceinline__ float bf2f(u16 v) {
    return __uint_as_float(((unsigned int)v) << 16);
}
__device__ __forceinline__ float softplus_f(float x) {
    return fmaxf(x, 0.0f) + log1pf(__expf(-fabsf(x)));
}
__device__ __forceinline__ float tanh_fast(float x) {
    const float e = __expf(2.0f * x);
    return 1.0f - 2.0f / (e + 1.0f);
}
__device__ __forceinline__ void async_cp16(u16* lds, const u16* g) {
    __builtin_amdgcn_global_load_lds(
        (const __attribute__((address_space(1))) unsigned int*)g,
        (__attribute__((address_space(3))) unsigned int*)lds, 16, 0, 0);
}

// ---------------------------------------------------------------------------
// fp32 -> bf16 enc conversion (also feeds context kernel)
// ---------------------------------------------------------------------------
__global__ __launch_bounds__(256) void conv_enc_kernel(const float* __restrict__ in,
                                                       u16* __restrict__ out) {
    const size_t i = (size_t)blockIdx.x * 256 + threadIdx.x;   // group of 8
    const float4* p = (const float4*)in + i * 2;
    const float4 a = p[0], b = p[1];
    u16x8 o;
    o[0] = f2bf(a.x); o[1] = f2bf(a.y); o[2] = f2bf(a.z); o[3] = f2bf(a.w);
    o[4] = f2bf(b.x); o[5] = f2bf(b.y); o[6] = f2bf(b.z); o[7] = f2bf(b.w);
    *((u16x8*)out + i) = o;
}

// ---------------------------------------------------------------------------
// WvT[n][k] = bf16(Wv[k][n]) via LDS tile transpose (coalesced both sides)
// grid (16 n-tiles, 8 k-tiles), tile 64x64
// ---------------------------------------------------------------------------
__global__ __launch_bounds__(256) void conv_wvT_kernel(const float* __restrict__ Wv,
                                                       u16* __restrict__ WvT) {
    __shared__ float tile[64 * 65];
    const int nt = blockIdx.x, kt = blockIdx.y, tid = threadIdx.x;
    for (int i = tid; i < 4096; i += 256) {
        const int kk = i >> 6, nn = i & 63;
        tile[kk * 65 + nn] = Wv[(size_t)(kt * 64 + kk) * IHD + nt * 64 + nn];
    }
    __syncthreads();
    for (int i = tid; i < 4096; i += 256) {
        const int nn = i >> 6, kk = i & 63;
        WvT[(size_t)(nt * 64 + nn) * 512 + kt * 64 + kk] = f2bf(tile[kk * 65 + nn]);
    }
}

// ---------------------------------------------------------------------------
// prep: query = dec@Wq+bq ; beta = sp(dec@Wb+bb) ; kappa += sp(dec@Wk+bk)
// grid (BSZ, 9): y<8 -> 128 query cols with 2-way k-split; y==8 -> beta/kappa
// ---------------------------------------------------------------------------
__global__ __launch_bounds__(256) void prep_kernel(
    const float* __restrict__ dec, const float* __restrict__ kappa_in,
    const float* __restrict__ Wq, const float* __restrict__ bq,
    const float* __restrict__ Wb, const float* __restrict__ bb,
    const float* __restrict__ Wk, const float* __restrict__ bk,
    float* __restrict__ query_ws, float* __restrict__ beta_ws,
    float* __restrict__ kappa_out)
{
    __shared__ float s_dec[DE];
    __shared__ float s_red[256];
    const int b = blockIdx.x, y = blockIdx.y, tid = threadIdx.x;
    for (int i = tid; i < DE; i += 256) s_dec[i] = dec[b * DE + i];
    __syncthreads();

    if (y < 8) {
        const int col = y * 128 + (tid & 127);
        const int kg = tid >> 7;
        float a = 0.f;
        const float* w = Wq + col;
        #pragma unroll 4
        for (int k = kg * 512; k < kg * 512 + 512; ++k)
            a = fmaf(s_dec[k], w[(size_t)k * IHD], a);
        s_red[tid] = a;
        __syncthreads();
        if (tid < 128)
            query_ws[(size_t)b * IHD + col] = s_red[tid] + s_red[tid + 128] + bq[col];
    } else {
        const int h = tid & 7, kg = tid >> 3;   // 32 k-groups of 32
        float ab = 0.f, ak = 0.f;
        for (int k = kg * 32; k < kg * 32 + 32; ++k) {
            const float d = s_dec[k];
            ab = fmaf(d, Wb[k * NHEADS + h], ab);
            ak = fmaf(d, Wk[k * NHEADS + h], ak);
        }
        s_red[tid] = ab;
        __syncthreads();
        for (int off = 128; off >= 8; off >>= 1) {
            if (tid < off) s_red[tid] += s_red[tid + off];
            __syncthreads();
        }
        const float abT = (tid < 8) ? s_red[tid] : 0.f;
        __syncthreads();
        s_red[tid] = ak;
        __syncthreads();
        for (int off = 128; off >= 8; off >>= 1) {
            if (tid < off) s_red[tid] += s_red[tid + off];
            __syncthreads();
        }
        if (tid < 8) {
            beta_ws[b * NHEADS + tid]   = softplus_f(bb[tid] + abT);
            kappa_out[b * NHEADS + tid] = kappa_in[b * NHEADS + tid]
                                        + softplus_f(bk[tid] + s_red[tid]);
        }
    }
}

// ---------------------------------------------------------------------------
// Main fused kernel. One block per 128-row m-tile (512 blocks). Loops over all
// 8 n-slices of IH: stage-1 MFMA GEMM (value = enc@Wv), tanh -> t-tile in LDS,
// stage-2 MFMA (t @ Wf) accumulated in registers across n-slices. Then score
// computed and stored in-block (no atomics, no separate score kernel).
// Staging uses global_load_lds(16B) with xor chunk-swizzle: LDS[m][c] holds
// global chunk c^(m&7), so frag ds_read_b128 (row stride 128B) spreads banks.
// ---------------------------------------------------------------------------
#define BM 128
#define BK 64

__global__ __launch_bounds__(256) void gemm_score_kernel(
    const u16* __restrict__ encb, const u16* __restrict__ wvT,
    const float* __restrict__ bv, const float* __restrict__ Wf,
    const float* __restrict__ bf_g, const float* __restrict__ mask,
    const float* __restrict__ query_ws, const float* __restrict__ beta_ws,
    const float* __restrict__ kappa_out, float* __restrict__ score_out)
{
    // LDS carve: [0,16384) Abuf | [16384,32768) Bbuf  (union with tT 34816 B)
    //            [34816,51216) WfB bf16[8192]+8 pad | [51216,55312) qb f32[1024]
    __shared__ __align__(16) unsigned char smem[55312];
    u16*   Ab  = (u16*)smem;                    // [128 rows][8 chunks][8 u16]
    u16*   Bb  = (u16*)(smem + 16384);
    u16*   tT  = (u16*)smem;                    // [128][136] u16 (row pad +8)
    u16*   WfB = (u16*)(smem + 34816);
    float* qb  = (float*)(smem + 51216);

    const int tid  = threadIdx.x;
    const int m0   = blockIdx.x * BM;
    const int b    = blockIdx.x >> 4;           // 16 m-tiles per batch
    const int lane = tid & 63;
    const int w    = tid >> 6;
    const int wr   = w >> 1, wc = w & 1;
    const int fr   = lane & 15, quad = lane >> 4;

    for (int i = tid; i < 1024; i += 256)
        qb[i] = query_ws[(size_t)b * IHD + i] + bv[i];
    for (int i = tid; i < 8200; i += 256)
        WfB[i] = (i < 8192) ? f2bf(Wf[i]) : (u16)0;
    // (first K-loop __syncthreads makes these visible before first use)

    floatx4 acc2[2] = {};

    for (int nn = 0; nn < 8; ++nn) {
        const int n0 = nn * 128;
        floatx4 acc[4][4] = {};

        for (int kt = 0; kt < 8; ++kt) {
            const int ko = kt * BK;
            #pragma unroll
            for (int r = 0; r < 4; ++r) {
                const int s  = r * 256 + tid;
                const int m  = s >> 3;
                const int cs = (s & 7) ^ (m & 7);
                async_cp16(Ab + (size_t)(r * 256 + (tid & 192)) * 8,
                           encb + (size_t)(m0 + m) * 512 + ko + cs * 8);
            }
            #pragma unroll
            for (int r = 0; r < 4; ++r) {
                const int s  = r * 256 + tid;
                const int m  = s >> 3;
                const int cs = (s & 7) ^ (m & 7);
                async_cp16(Bb + (size_t)(r * 256 + (tid & 192)) * 8,
                           wvT + (size_t)(n0 + m) * 512 + ko + cs * 8);
            }
            __syncthreads();
            #pragma unroll
            for (int s2 = 0; s2 < 2; ++s2) {
                bf16x8 af[4], bfr[4];
                #pragma unroll
                for (int t = 0; t < 4; ++t) {
                    const int ma = wr * 64 + t * 16 + fr;
                    const int ca = (s2 * 4 + quad) ^ (ma & 7);
                    af[t] = *(const bf16x8*)&Ab[ma * 64 + ca * 8];
                    const int nb = wc * 64 + t * 16 + fr;
                    const int cb = (s2 * 4 + quad) ^ (nb & 7);
                    bfr[t] = *(const bf16x8*)&Bb[nb * 64 + cb * 8];
                }
                #pragma unroll
                for (int mt = 0; mt < 4; ++mt)
                    #pragma unroll
                    for (int nt = 0; nt < 4; ++nt)
                        acc[mt][nt] = __builtin_amdgcn_mfma_f32_16x16x32_bf16(
                            af[mt], bfr[nt], acc[mt][nt], 0, 0, 0);
            }
            __syncthreads();
        }

        // ---- epilogue A: t = tanh(value + query + bv) -> LDS (bf16)
        #pragma unroll
        for (int mt = 0; mt < 4; ++mt) {
            #pragma unroll
            for (int nt = 0; nt < 4; ++nt) {
                const int col = wc * 64 + nt * 16 + fr;
                const float qv = qb[n0 + col];
                #pragma unroll
                for (int reg = 0; reg < 4; ++reg) {
                    const int row = wr * 64 + mt * 16 + quad * 4 + reg;
                    tT[row * 136 + col] = f2bf(tanh_fast(acc[mt][nt][reg] + qv));
                }
            }
        }
        __syncthreads();

        // ---- epilogue B: stage-2 MFMA  P += t(128x128) @ Wf_slice(128x8)
        bf16x8 wfr[4];
        #pragma unroll
        for (int ks = 0; ks < 4; ++ks)
            #pragma unroll
            for (int j = 0; j < 8; ++j)
                wfr[ks][j] = *(const __bf16*)&WfB[(n0 + ks * 32 + quad * 8 + j) * 8 + fr];
        #pragma unroll
        for (int t2 = 0; t2 < 2; ++t2) {
            const int mtile = w * 2 + t2;
            #pragma unroll
            for (int ks = 0; ks < 4; ++ks) {
                const bf16x8 ta = *(const bf16x8*)&tT[(mtile * 16 + fr) * 136
                                                      + ks * 32 + quad * 8];
                acc2[t2] = __builtin_amdgcn_mfma_f32_16x16x32_bf16(
                    ta, wfr[ks], acc2[t2], 0, 0, 0);
            }
        }
        __syncthreads();   // protect tT before next n-iter staging
    }

    // ---- score phase: softplus(P + bf) * mask * exp(-beta*(kappa-u)^2)
    if (fr < NHEADS) {
        const float bfh = bf_g[fr];
        const float bet = beta_ws[b * NHEADS + fr];
        const float kap = kappa_out[b * NHEADS + fr];
        #pragma unroll
        for (int t2 = 0; t2 < 2; ++t2) {
            #pragma unroll
            for (int reg = 0; reg < 4; ++reg) {
                const int m_local = w * 32 + t2 * 16 + quad * 4 + reg;
                const int row = m0 + m_local;
                const int s = row & 2047;
                const float alpha = softplus_f(acc2[t2][reg] + bfh) * mask[row];
                const float du = kap - (float)s;
                score_out[(size_t)row * NHEADS + fr] = alpha * __expf(-bet * du * du);
            }
        }
    }
}

// ---------------------------------------------------------------------------
// context[b,h,e] = sum_s score[b,s,h] * enc[b,s,e]  -- bf16x8 vector loads
// grid (b, s-chunk of 256); thread: 8 consecutive e x 8 h accumulators
// ---------------------------------------------------------------------------
__global__ __launch_bounds__(256) void context_kernel(
    const u16* __restrict__ encb, const float* __restrict__ score,
    float* __restrict__ ctx_ws)
{
    __shared__ float s_sc[256 * NHEADS];
    const int b = blockIdx.x, ch = blockIdx.y, tid = threadIdx.x;
    const int e8 = (tid & 63) * 8;
    const int sg = tid >> 6;                     // 4 s-subgroups of 64 rows
    const size_t srow0 = (size_t)b * SEQL + ch * 256;

    for (int i = tid; i < 256 * NHEADS; i += 256)
        s_sc[i] = score[srow0 * NHEADS + i];
    __syncthreads();

    float acc[NHEADS][8] = {};
    for (int si = 0; si < 64; ++si) {
        const int s = sg * 64 + si;
        const u16x8 ev = *(const u16x8*)&encb[(srow0 + s) * ENCD + e8];
        float ef[8];
        #pragma unroll
        for (int j = 0; j < 8; ++j) ef[j] = bf2f(ev[j]);
        const float4 sc0 = *(const float4*)&s_sc[s * NHEADS];
        const float4 sc1 = *(const float4*)&s_sc[s * NHEADS + 4];
        const float sch[8] = {sc0.x, sc0.y, sc0.z, sc0.w, sc1.x, sc1.y, sc1.z, sc1.w};
        #pragma unroll
        for (int h = 0; h < NHEADS; ++h)
            #pragma unroll
            for (int j = 0; j < 8; ++j)
                acc[h][j] = fmaf(sch[h], ef[j], acc[h][j]);
    }
    #pragma unroll
    for (int h = 0; h < NHEADS; ++h)
        #pragma unroll
        for (int j = 0; j < 8; ++j)
            atomicAdd(&ctx_ws[(size_t)b * (NHEADS * ENCD) + h * ENCD + e8 + j],
                      acc[h][j]);
}

// ---------------------------------------------------------------------------
// out_ctx[b,j] = ctx[b,:] @ Wfc[:,j] + bfc[j]
// grid (jc=16, ks=8): 32 j-cols x all 32 b; Wfc element read exactly once.
// ---------------------------------------------------------------------------
__global__ __launch_bounds__(256) void final_kernel(
    const float* __restrict__ ctx_ws, const float* __restrict__ Wfc,
    const float* __restrict__ bfc, float* __restrict__ out_ctx)
{
    __shared__ float s_ctx[32][128];
    const int jc = blockIdx.x, ks = blockIdx.y, tid = threadIdx.x;
    const int jl = tid & 31, bg = tid >> 5;
    const int j = jc * 32 + jl;
    float a0 = 0.f, a1 = 0.f, a2 = 0.f, a3 = 0.f;

    for (int t = 0; t < 4; ++t) {
        const int k0 = ks * 512 + t * 128;
        __syncthreads();
        for (int i = tid; i < 32 * 128; i += 256) {
            const int bb2 = i >> 7, kk = i & 127;
            s_ctx[bb2][kk] = ctx_ws[(size_t)bb2 * (NHEADS * ENCD) + k0 + kk];
        }
        __syncthreads();
        for (int kk = 0; kk < 128; ++kk) {
            const float wv = Wfc[(size_t)(k0 + kk) * ENCD + j];
            a0 = fmaf(s_ctx[bg * 4 + 0][kk], wv, a0);
            a1 = fmaf(s_ctx[bg * 4 + 1][kk], wv, a1);
            a2 = fmaf(s_ctx[bg * 4 + 2][kk], wv, a2);
            a3 = fmaf(s_ctx[bg * 4 + 3][kk], wv, a3);
        }
    }
    const float bias = (ks == 0) ? bfc[j] : 0.0f;
    atomicAdd(&out_ctx[(bg * 4 + 0) * ENCD + j], a0 + bias);
    atomicAdd(&out_ctx[(bg * 4 + 1) * ENCD + j], a1 + bias);
    atomicAdd(&out_ctx[(bg * 4 + 2) * ENCD + j], a2 + bias);
    atomicAdd(&out_ctx[(bg * 4 + 3) * ENCD + j], a3 + bias);
}

// ---------------------------------------------------------------------------
extern "C" void kernel_launch(void* const* d_in, const int* in_sizes, int n_in,
                              void* d_out, int out_size, void* d_ws, size_t ws_size,
                              hipStream_t stream)
{
    const float* enc   = (const float*)d_in[0];
    const float* dec   = (const float*)d_in[1];
    const float* kapin = (const float*)d_in[2];
    const float* mask  = (const float*)d_in[3];
    const float* Wv    = (const float*)d_in[4];
    const float* bv    = (const float*)d_in[5];
    const float* Wq    = (const float*)d_in[6];
    const float* bq    = (const float*)d_in[7];
    const float* Wf    = (const float*)d_in[8];
    const float* bf    = (const float*)d_in[9];
    const float* Wb    = (const float*)d_in[10];
    const float* bb    = (const float*)d_in[11];
    const float* Wk    = (const float*)d_in[12];
    const float* bk    = (const float*)d_in[13];
    const float* Wfc   = (const float*)d_in[14];
    const float* bfc   = (const float*)d_in[15];

    // outputs: context(32*512) | kappa(32*8) | score(32*2048*8)
    float* out       = (float*)d_out;
    float* out_ctx   = out;
    float* out_kappa = out + 16384;
    float* out_score = out + 16640;

    // workspace layout (bytes)
    char* w = (char*)d_ws;
    u16*   enc_bf  = (u16*)w;                    // 67108864 B
    u16*   wvT     = (u16*)(w + 67108864);       //  1048576 B
    float* q_ws    = (float*)(w + 68157440);     //   131072 B
    float* beta_ws = (float*)(w + 68288512);     //     1024 B
    float* ctx_ws  = (float*)(w + 68289536);     //   524288 B

    hipMemsetAsync(ctx_ws, 0, 524288, stream);
    hipMemsetAsync(out_ctx, 0, 16384 * sizeof(float), stream);

    conv_enc_kernel<<<dim3(16384), dim3(256), 0, stream>>>(enc, enc_bf);
    conv_wvT_kernel<<<dim3(16, 8), dim3(256), 0, stream>>>(Wv, wvT);

    prep_kernel<<<dim3(BSZ, 9), dim3(256), 0, stream>>>(
        dec, kapin, Wq, bq, Wb, bb, Wk, bk, q_ws, beta_ws, out_kappa);

    gemm_score_kernel<<<dim3((BSZ * SEQL) / BM), dim3(256), 0, stream>>>(
        enc_bf, wvT, bv, Wf, bf, mask, q_ws, beta_ws, out_kappa, out_score);

    context_kernel<<<dim3(BSZ, 8), dim3(256), 0, stream>>>(
        enc_bf, out_score, ctx_ws);

    final_kernel<<<dim3(16, 8), dim3(256), 0, stream>>>(
        ctx_ws, Wfc, bfc, out_ctx);
}

// Round 4
// 509.833 us; speedup vs baseline: 10.5522x; 1.3634x over previous
//
#include <hip/hip_runtime.h>
#include <cstdint>
#include <cstddef>

#define BSZ    32
#define SEQL   2048
#define ENCD   512
#define DE     1024   // DEC + ENC
#define NHEADS 8
#define IHD    1024   // INTERM * HEADS

typedef unsigned short u16;
typedef __bf16 bf16x8 __attribute__((ext_vector_type(8)));
typedef float floatx4 __attribute__((ext_vector_type(4)));
typedef unsigned short u16x8 __attribute__((ext_vector_type(8)));

__device__ __forceinline__ u16 f2bf(float f) {
    unsigned int u = __float_as_uint(f);
    u = (u + 0x7FFFu + ((u >> 16) & 1u)) >> 16;   // RNE
    return (u16)u;
}
__device__ __forceinline__ float bf2f(u16 v) {
    return __uint_as_float(((unsigned int)v) << 16);
}
__device__ __forceinline__ float softplus_f(float x) {
    return fmaxf(x, 0.0f) + log1pf(__expf(-fabsf(x)));
}
__device__ __forceinline__ float tanh_fast(float x) {
    const float e = __expf(2.0f * x);
    return 1.0f - 2.0f / (e + 1.0f);
}
__device__ __forceinline__ void async_cp16(u16* lds, const u16* g) {
    __builtin_amdgcn_global_load_lds(
        (const __attribute__((address_space(1))) unsigned int*)g,
        (__attribute__((address_space(3))) unsigned int*)lds, 16, 0, 0);
}

// ---------------------------------------------------------------------------
// fp32 -> bf16 enc conversion (feeds gemm and context kernels)
// ---------------------------------------------------------------------------
__global__ __launch_bounds__(256) void conv_enc_kernel(const float* __restrict__ in,
                                                       u16* __restrict__ out) {
    const size_t i = (size_t)blockIdx.x * 256 + threadIdx.x;   // group of 8
    const float4* p = (const float4*)in + i * 2;
    const float4 a = p[0], b = p[1];
    u16x8 o;
    o[0] = f2bf(a.x); o[1] = f2bf(a.y); o[2] = f2bf(a.z); o[3] = f2bf(a.w);
    o[4] = f2bf(b.x); o[5] = f2bf(b.y); o[6] = f2bf(b.z); o[7] = f2bf(b.w);
    *((u16x8*)out + i) = o;
}

// ---------------------------------------------------------------------------
// WvT[n][k] = bf16(Wv[k][n]) via LDS tile transpose (coalesced both sides)
// ---------------------------------------------------------------------------
__global__ __launch_bounds__(256) void conv_wvT_kernel(const float* __restrict__ Wv,
                                                       u16* __restrict__ WvT) {
    __shared__ float tile[64 * 65];
    const int nt = blockIdx.x, kt = blockIdx.y, tid = threadIdx.x;
    for (int i = tid; i < 4096; i += 256) {
        const int kk = i >> 6, nn = i & 63;
        tile[kk * 65 + nn] = Wv[(size_t)(kt * 64 + kk) * IHD + nt * 64 + nn];
    }
    __syncthreads();
    for (int i = tid; i < 4096; i += 256) {
        const int nn = i >> 6, kk = i & 63;
        WvT[(size_t)(nt * 64 + nn) * 512 + kt * 64 + kk] = f2bf(tile[kk * 65 + nn]);
    }
}

// ---------------------------------------------------------------------------
// prep: query = dec@Wq+bq ; beta = sp(dec@Wb+bb) ; kappa += sp(dec@Wk+bk)
// ---------------------------------------------------------------------------
__global__ __launch_bounds__(256) void prep_kernel(
    const float* __restrict__ dec, const float* __restrict__ kappa_in,
    const float* __restrict__ Wq, const float* __restrict__ bq,
    const float* __restrict__ Wb, const float* __restrict__ bb,
    const float* __restrict__ Wk, const float* __restrict__ bk,
    float* __restrict__ query_ws, float* __restrict__ beta_ws,
    float* __restrict__ kappa_out)
{
    __shared__ float s_dec[DE];
    __shared__ float s_red[256];
    const int b = blockIdx.x, y = blockIdx.y, tid = threadIdx.x;
    for (int i = tid; i < DE; i += 256) s_dec[i] = dec[b * DE + i];
    __syncthreads();

    if (y < 8) {
        const int col = y * 128 + (tid & 127);
        const int kg = tid >> 7;
        float a = 0.f;
        const float* w = Wq + col;
        #pragma unroll 4
        for (int k = kg * 512; k < kg * 512 + 512; ++k)
            a = fmaf(s_dec[k], w[(size_t)k * IHD], a);
        s_red[tid] = a;
        __syncthreads();
        if (tid < 128)
            query_ws[(size_t)b * IHD + col] = s_red[tid] + s_red[tid + 128] + bq[col];
    } else {
        const int h = tid & 7, kg = tid >> 3;   // 32 k-groups of 32
        float ab = 0.f, ak = 0.f;
        for (int k = kg * 32; k < kg * 32 + 32; ++k) {
            const float d = s_dec[k];
            ab = fmaf(d, Wb[k * NHEADS + h], ab);
            ak = fmaf(d, Wk[k * NHEADS + h], ak);
        }
        s_red[tid] = ab;
        __syncthreads();
        for (int off = 128; off >= 8; off >>= 1) {
            if (tid < off) s_red[tid] += s_red[tid + off];
            __syncthreads();
        }
        const float abT = (tid < 8) ? s_red[tid] : 0.f;
        __syncthreads();
        s_red[tid] = ak;
        __syncthreads();
        for (int off = 128; off >= 8; off >>= 1) {
            if (tid < off) s_red[tid] += s_red[tid + off];
            __syncthreads();
        }
        if (tid < 8) {
            beta_ws[b * NHEADS + tid]   = softplus_f(bb[tid] + abT);
            kappa_out[b * NHEADS + tid] = kappa_in[b * NHEADS + tid]
                                        + softplus_f(bk[tid] + s_red[tid]);
        }
    }
}

// ---------------------------------------------------------------------------
// Main fused kernel (unchanged from round 3): one block per 128-row m-tile,
// loops 8 n-slices: stage-1 MFMA (value=enc@Wv) -> tanh -> tT LDS ->
// stage-2 MFMA (t@Wf) -> score in-block.
// ---------------------------------------------------------------------------
#define BM 128
#define BK 64

__global__ __launch_bounds__(256) void gemm_score_kernel(
    const u16* __restrict__ encb, const u16* __restrict__ wvT,
    const float* __restrict__ bv, const float* __restrict__ Wf,
    const float* __restrict__ bf_g, const float* __restrict__ mask,
    const float* __restrict__ query_ws, const float* __restrict__ beta_ws,
    const float* __restrict__ kappa_out, float* __restrict__ score_out)
{
    __shared__ __align__(16) unsigned char smem[55312];
    u16*   Ab  = (u16*)smem;                    // [128 rows][8 chunks][8 u16]
    u16*   Bb  = (u16*)(smem + 16384);
    u16*   tT  = (u16*)smem;                    // [128][136] u16 (union w/ Ab|Bb)
    u16*   WfB = (u16*)(smem + 34816);
    float* qb  = (float*)(smem + 51216);

    const int tid  = threadIdx.x;
    const int m0   = blockIdx.x * BM;
    const int b    = blockIdx.x >> 4;
    const int lane = tid & 63;
    const int w    = tid >> 6;
    const int wr   = w >> 1, wc = w & 1;
    const int fr   = lane & 15, quad = lane >> 4;

    for (int i = tid; i < 1024; i += 256)
        qb[i] = query_ws[(size_t)b * IHD + i] + bv[i];
    for (int i = tid; i < 8200; i += 256)
        WfB[i] = (i < 8192) ? f2bf(Wf[i]) : (u16)0;

    floatx4 acc2[2] = {};

    for (int nn = 0; nn < 8; ++nn) {
        const int n0 = nn * 128;
        floatx4 acc[4][4] = {};

        for (int kt = 0; kt < 8; ++kt) {
            const int ko = kt * BK;
            #pragma unroll
            for (int r = 0; r < 4; ++r) {
                const int s  = r * 256 + tid;
                const int m  = s >> 3;
                const int cs = (s & 7) ^ (m & 7);
                async_cp16(Ab + (size_t)(r * 256 + (tid & 192)) * 8,
                           encb + (size_t)(m0 + m) * 512 + ko + cs * 8);
            }
            #pragma unroll
            for (int r = 0; r < 4; ++r) {
                const int s  = r * 256 + tid;
                const int m  = s >> 3;
                const int cs = (s & 7) ^ (m & 7);
                async_cp16(Bb + (size_t)(r * 256 + (tid & 192)) * 8,
                           wvT + (size_t)(n0 + m) * 512 + ko + cs * 8);
            }
            __syncthreads();
            #pragma unroll
            for (int s2 = 0; s2 < 2; ++s2) {
                bf16x8 af[4], bfr[4];
                #pragma unroll
                for (int t = 0; t < 4; ++t) {
                    const int ma = wr * 64 + t * 16 + fr;
                    const int ca = (s2 * 4 + quad) ^ (ma & 7);
                    af[t] = *(const bf16x8*)&Ab[ma * 64 + ca * 8];
                    const int nb = wc * 64 + t * 16 + fr;
                    const int cb = (s2 * 4 + quad) ^ (nb & 7);
                    bfr[t] = *(const bf16x8*)&Bb[nb * 64 + cb * 8];
                }
                #pragma unroll
                for (int mt = 0; mt < 4; ++mt)
                    #pragma unroll
                    for (int nt = 0; nt < 4; ++nt)
                        acc[mt][nt] = __builtin_amdgcn_mfma_f32_16x16x32_bf16(
                            af[mt], bfr[nt], acc[mt][nt], 0, 0, 0);
            }
            __syncthreads();
        }

        #pragma unroll
        for (int mt = 0; mt < 4; ++mt) {
            #pragma unroll
            for (int nt = 0; nt < 4; ++nt) {
                const int col = wc * 64 + nt * 16 + fr;
                const float qv = qb[n0 + col];
                #pragma unroll
                for (int reg = 0; reg < 4; ++reg) {
                    const int row = wr * 64 + mt * 16 + quad * 4 + reg;
                    tT[row * 136 + col] = f2bf(tanh_fast(acc[mt][nt][reg] + qv));
                }
            }
        }
        __syncthreads();

        bf16x8 wfr[4];
        #pragma unroll
        for (int ks = 0; ks < 4; ++ks)
            #pragma unroll
            for (int j = 0; j < 8; ++j)
                wfr[ks][j] = *(const __bf16*)&WfB[(n0 + ks * 32 + quad * 8 + j) * 8 + fr];
        #pragma unroll
        for (int t2 = 0; t2 < 2; ++t2) {
            const int mtile = w * 2 + t2;
            #pragma unroll
            for (int ks = 0; ks < 4; ++ks) {
                const bf16x8 ta = *(const bf16x8*)&tT[(mtile * 16 + fr) * 136
                                                      + ks * 32 + quad * 8];
                acc2[t2] = __builtin_amdgcn_mfma_f32_16x16x32_bf16(
                    ta, wfr[ks], acc2[t2], 0, 0, 0);
            }
        }
        __syncthreads();
    }

    if (fr < NHEADS) {
        const float bfh = bf_g[fr];
        const float bet = beta_ws[b * NHEADS + fr];
        const float kap = kappa_out[b * NHEADS + fr];
        #pragma unroll
        for (int t2 = 0; t2 < 2; ++t2) {
            #pragma unroll
            for (int reg = 0; reg < 4; ++reg) {
                const int m_local = w * 32 + t2 * 16 + quad * 4 + reg;
                const int row = m0 + m_local;
                const int s = row & 2047;
                const float alpha = softplus_f(acc2[t2][reg] + bfh) * mask[row];
                const float du = kap - (float)s;
                score_out[(size_t)row * NHEADS + fr] = alpha * __expf(-bet * du * du);
            }
        }
    }
}

// ---------------------------------------------------------------------------
// context partials: part[sc][b][h][e] = sum_{s in chunk} score[b,s,h]*enc[b,s,e]
// grid (b=32, sc=16). Wave w owns heads {2w,2w+1} x all 512 e; lane owns 8 e
// (u16x8 16B loads). Score broadcast from LDS. Plain stores -> NO atomics.
// ---------------------------------------------------------------------------
__global__ __launch_bounds__(256) void context_kernel(
    const u16* __restrict__ encb, const float* __restrict__ score,
    float* __restrict__ ctx_part)
{
    __shared__ float s_sc[128 * NHEADS];
    const int b = blockIdx.x, sc = blockIdx.y, tid = threadIdx.x;
    const int lane = tid & 63, w = tid >> 6;
    const int e8 = lane * 8;
    const size_t srow0 = (size_t)b * SEQL + sc * 128;

    for (int i = tid; i < 128 * NHEADS; i += 256)
        s_sc[i] = score[srow0 * NHEADS + i];
    __syncthreads();

    float acc0[8] = {}, acc1[8] = {};
    const u16* ep = encb + srow0 * ENCD + e8;
    #pragma unroll 4
    for (int s = 0; s < 128; ++s) {
        const u16x8 ev = *(const u16x8*)(ep + (size_t)s * ENCD);
        const float2 sc2 = *(const float2*)&s_sc[s * NHEADS + 2 * w];
        #pragma unroll
        for (int j = 0; j < 8; ++j) {
            const float e = bf2f(ev[j]);
            acc0[j] = fmaf(sc2.x, e, acc0[j]);
            acc1[j] = fmaf(sc2.y, e, acc1[j]);
        }
    }

    float* outp = ctx_part + ((size_t)sc * BSZ + b) * (NHEADS * ENCD);
    *(float4*)&outp[(2 * w + 0) * ENCD + e8]     = make_float4(acc0[0], acc0[1], acc0[2], acc0[3]);
    *(float4*)&outp[(2 * w + 0) * ENCD + e8 + 4] = make_float4(acc0[4], acc0[5], acc0[6], acc0[7]);
    *(float4*)&outp[(2 * w + 1) * ENCD + e8]     = make_float4(acc1[0], acc1[1], acc1[2], acc1[3]);
    *(float4*)&outp[(2 * w + 1) * ENCD + e8 + 4] = make_float4(acc1[4], acc1[5], acc1[6], acc1[7]);
}

// ---------------------------------------------------------------------------
// ctx_ws[i] = sum_sc part[sc][i]   (i < 32*8*512 = 131072)
// ---------------------------------------------------------------------------
__global__ __launch_bounds__(256) void ctx_reduce_kernel(
    const float* __restrict__ part, float* __restrict__ ctx_ws)
{
    const int i = blockIdx.x * 256 + threadIdx.x;
    float a = 0.f;
    #pragma unroll
    for (int sc = 0; sc < 16; ++sc)
        a += part[(size_t)sc * 131072 + i];
    ctx_ws[i] = a;
}

// ---------------------------------------------------------------------------
// out_ctx[b,j] = ctx[b,:] @ Wfc[:,j] + bfc[j]
// ---------------------------------------------------------------------------
__global__ __launch_bounds__(256) void final_kernel(
    const float* __restrict__ ctx_ws, const float* __restrict__ Wfc,
    const float* __restrict__ bfc, float* __restrict__ out_ctx)
{
    __shared__ float s_ctx[32][128];
    const int jc = blockIdx.x, ks = blockIdx.y, tid = threadIdx.x;
    const int jl = tid & 31, bg = tid >> 5;
    const int j = jc * 32 + jl;
    float a0 = 0.f, a1 = 0.f, a2 = 0.f, a3 = 0.f;

    for (int t = 0; t < 4; ++t) {
        const int k0 = ks * 512 + t * 128;
        __syncthreads();
        for (int i = tid; i < 32 * 128; i += 256) {
            const int bb2 = i >> 7, kk = i & 127;
            s_ctx[bb2][kk] = ctx_ws[(size_t)bb2 * (NHEADS * ENCD) + k0 + kk];
        }
        __syncthreads();
        for (int kk = 0; kk < 128; ++kk) {
            const float wv = Wfc[(size_t)(k0 + kk) * ENCD + j];
            a0 = fmaf(s_ctx[bg * 4 + 0][kk], wv, a0);
            a1 = fmaf(s_ctx[bg * 4 + 1][kk], wv, a1);
            a2 = fmaf(s_ctx[bg * 4 + 2][kk], wv, a2);
            a3 = fmaf(s_ctx[bg * 4 + 3][kk], wv, a3);
        }
    }
    const float bias = (ks == 0) ? bfc[j] : 0.0f;
    atomicAdd(&out_ctx[(bg * 4 + 0) * ENCD + j], a0 + bias);
    atomicAdd(&out_ctx[(bg * 4 + 1) * ENCD + j], a1 + bias);
    atomicAdd(&out_ctx[(bg * 4 + 2) * ENCD + j], a2 + bias);
    atomicAdd(&out_ctx[(bg * 4 + 3) * ENCD + j], a3 + bias);
}

// ---------------------------------------------------------------------------
extern "C" void kernel_launch(void* const* d_in, const int* in_sizes, int n_in,
                              void* d_out, int out_size, void* d_ws, size_t ws_size,
                              hipStream_t stream)
{
    const float* enc   = (const float*)d_in[0];
    const float* dec   = (const float*)d_in[1];
    const float* kapin = (const float*)d_in[2];
    const float* mask  = (const float*)d_in[3];
    const float* Wv    = (const float*)d_in[4];
    const float* bv    = (const float*)d_in[5];
    const float* Wq    = (const float*)d_in[6];
    const float* bq    = (const float*)d_in[7];
    const float* Wf    = (const float*)d_in[8];
    const float* bf    = (const float*)d_in[9];
    const float* Wb    = (const float*)d_in[10];
    const float* bb    = (const float*)d_in[11];
    const float* Wk    = (const float*)d_in[12];
    const float* bk    = (const float*)d_in[13];
    const float* Wfc   = (const float*)d_in[14];
    const float* bfc   = (const float*)d_in[15];

    // outputs: context(32*512) | kappa(32*8) | score(32*2048*8)
    float* out       = (float*)d_out;
    float* out_ctx   = out;
    float* out_kappa = out + 16384;
    float* out_score = out + 16640;

    // workspace layout (bytes)
    char* w = (char*)d_ws;
    u16*   enc_bf   = (u16*)w;                     // 67108864 B
    float* ctx_part = (float*)(w + 67108864);      //  8388608 B
    u16*   wvT      = (u16*)(w + 75497472);        //  1048576 B
    float* q_ws     = (float*)(w + 76546048);      //   131072 B
    float* beta_ws  = (float*)(w + 76677120);      //     1024 B
    float* ctx_ws   = (float*)(w + 76678144);      //   524288 B
                                                   // total 77202432 B

    hipMemsetAsync(out_ctx, 0, 16384 * sizeof(float), stream);

    conv_enc_kernel<<<dim3(16384), dim3(256), 0, stream>>>(enc, enc_bf);
    conv_wvT_kernel<<<dim3(16, 8), dim3(256), 0, stream>>>(Wv, wvT);

    prep_kernel<<<dim3(BSZ, 9), dim3(256), 0, stream>>>(
        dec, kapin, Wq, bq, Wb, bb, Wk, bk, q_ws, beta_ws, out_kappa);

    gemm_score_kernel<<<dim3((BSZ * SEQL) / BM), dim3(256), 0, stream>>>(
        enc_bf, wvT, bv, Wf, bf, mask, q_ws, beta_ws, out_kappa, out_score);

    context_kernel<<<dim3(BSZ, 16), dim3(256), 0, stream>>>(
        enc_bf, out_score, ctx_part);

    ctx_reduce_kernel<<<dim3(512), dim3(256), 0, stream>>>(ctx_part, ctx_ws);

    final_kernel<<<dim3(16, 8), dim3(256), 0, stream>>>(
        ctx_ws, Wfc, bfc, out_ctx);
}

// Round 5
// 491.194 us; speedup vs baseline: 10.9526x; 1.0379x over previous
//
#include <hip/hip_runtime.h>
#include <cstdint>
#include <cstddef>

#define BSZ    32
#define SEQL   2048
#define ENCD   512
#define DE     1024   // DEC + ENC
#define NHEADS 8
#define IHD    1024   // INTERM * HEADS

typedef unsigned short u16;
typedef __bf16 bf16x8 __attribute__((ext_vector_type(8)));
typedef float floatx4 __attribute__((ext_vector_type(4)));
typedef unsigned short u16x8 __attribute__((ext_vector_type(8)));

__device__ __forceinline__ u16 f2bf(float f) {
    unsigned int u = __float_as_uint(f);
    u = (u + 0x7FFFu + ((u >> 16) & 1u)) >> 16;   // RNE
    return (u16)u;
}
__device__ __forceinline__ float bf2f(u16 v) {
    return __uint_as_float(((unsigned int)v) << 16);
}
__device__ __forceinline__ float softplus_f(float x) {
    return fmaxf(x, 0.0f) + log1pf(__expf(-fabsf(x)));
}
__device__ __forceinline__ float tanh_fast(float x) {
    const float e = __expf(2.0f * x);
    return 1.0f - 2.0f / (e + 1.0f);
}
__device__ __forceinline__ void async_cp16(u16* lds, const u16* g) {
    __builtin_amdgcn_global_load_lds(
        (const __attribute__((address_space(1))) unsigned int*)g,
        (__attribute__((address_space(3))) unsigned int*)lds, 16, 0, 0);
}

// ---------------------------------------------------------------------------
// fp32 -> bf16 enc conversion (feeds gemm and context kernels)
// ---------------------------------------------------------------------------
__global__ __launch_bounds__(256) void conv_enc_kernel(const float* __restrict__ in,
                                                       u16* __restrict__ out) {
    const size_t i = (size_t)blockIdx.x * 256 + threadIdx.x;   // group of 8
    const float4* p = (const float4*)in + i * 2;
    const float4 a = p[0], b = p[1];
    u16x8 o;
    o[0] = f2bf(a.x); o[1] = f2bf(a.y); o[2] = f2bf(a.z); o[3] = f2bf(a.w);
    o[4] = f2bf(b.x); o[5] = f2bf(b.y); o[6] = f2bf(b.z); o[7] = f2bf(b.w);
    *((u16x8*)out + i) = o;
}

// ---------------------------------------------------------------------------
// bid<128: WvT[n][k] = bf16(Wv[k][n]) 64x64 LDS tile transpose
// bid==128: Wf -> bf16 (8192 elems + 8 pad zeros)
// ---------------------------------------------------------------------------
__global__ __launch_bounds__(256) void conv_w_kernel(const float* __restrict__ Wv,
                                                     const float* __restrict__ Wf,
                                                     u16* __restrict__ WvT,
                                                     u16* __restrict__ wfb) {
    __shared__ float tile[64 * 65];
    const int bid = blockIdx.x, tid = threadIdx.x;
    if (bid == 128) {
        for (int i = tid; i < 8200; i += 256)
            wfb[i] = (i < 8192) ? f2bf(Wf[i]) : (u16)0;
        return;
    }
    const int nt = bid & 15, kt = bid >> 4;
    for (int i = tid; i < 4096; i += 256) {
        const int kk = i >> 6, nn = i & 63;
        tile[kk * 65 + nn] = Wv[(size_t)(kt * 64 + kk) * IHD + nt * 64 + nn];
    }
    __syncthreads();
    for (int i = tid; i < 4096; i += 256) {
        const int nn = i >> 6, kk = i & 63;
        WvT[(size_t)(nt * 64 + nn) * 512 + kt * 64 + kk] = f2bf(tile[kk * 65 + nn]);
    }
}

// ---------------------------------------------------------------------------
// prep: grid (BSZ, 33). y<32: 32 query cols, 8-way k-split + LDS reduce.
//       y==32: beta = sp(dec@Wb+bb); kappa += sp(dec@Wk+bk)
// ---------------------------------------------------------------------------
__global__ __launch_bounds__(256) void prep_kernel(
    const float* __restrict__ dec, const float* __restrict__ kappa_in,
    const float* __restrict__ Wq, const float* __restrict__ bq,
    const float* __restrict__ Wb, const float* __restrict__ bb,
    const float* __restrict__ Wk, const float* __restrict__ bk,
    float* __restrict__ query_ws, float* __restrict__ beta_ws,
    float* __restrict__ kappa_out)
{
    __shared__ float s_dec[DE];
    __shared__ float s_red[256];
    const int b = blockIdx.x, y = blockIdx.y, tid = threadIdx.x;
    for (int i = tid; i < DE; i += 256) s_dec[i] = dec[b * DE + i];
    __syncthreads();

    if (y < 32) {
        const int cl = tid & 31, kg = tid >> 5;
        const int col = y * 32 + cl;
        float a = 0.f;
        const float* w = Wq + col;
        #pragma unroll 4
        for (int k = kg * 128; k < kg * 128 + 128; ++k)
            a = fmaf(s_dec[k], w[(size_t)k * IHD], a);
        s_red[tid] = a;
        __syncthreads();
        if (tid < 32) {
            float s = 0.f;
            #pragma unroll
            for (int i = 0; i < 8; ++i) s += s_red[i * 32 + tid];
            query_ws[(size_t)b * IHD + col] = s + bq[col];
        }
    } else {
        const int h = tid & 7, kg = tid >> 3;   // 32 k-groups of 32
        float ab = 0.f, ak = 0.f;
        for (int k = kg * 32; k < kg * 32 + 32; ++k) {
            const float d = s_dec[k];
            ab = fmaf(d, Wb[k * NHEADS + h], ab);
            ak = fmaf(d, Wk[k * NHEADS + h], ak);
        }
        s_red[tid] = ab;
        __syncthreads();
        for (int off = 128; off >= 8; off >>= 1) {
            if (tid < off) s_red[tid] += s_red[tid + off];
            __syncthreads();
        }
        const float abT = (tid < 8) ? s_red[tid] : 0.f;
        __syncthreads();
        s_red[tid] = ak;
        __syncthreads();
        for (int off = 128; off >= 8; off >>= 1) {
            if (tid < off) s_red[tid] += s_red[tid + off];
            __syncthreads();
        }
        if (tid < 8) {
            beta_ws[b * NHEADS + tid]   = softplus_f(bb[tid] + abT);
            kappa_out[b * NHEADS + tid] = kappa_in[b * NHEADS + tid]
                                        + softplus_f(bk[tid] + s_red[tid]);
        }
    }
}

// ---------------------------------------------------------------------------
// Main fused kernel. BM=64 -> 1024 blocks (4 blocks/CU), LDS 24.6 KB.
// Per block: loop 8 n-slices of IH: stage-1 MFMA (value=enc@Wv, 64x128 tile),
// tanh -> tT LDS, stage-2 MFMA (t@Wf) acc across slices, score in-block.
// Wf(bf16) + query read from global (L1-resident), not LDS.
// ---------------------------------------------------------------------------
#define BM 64
#define BN 128
#define BK 64

__global__ __launch_bounds__(256, 4) void gemm_score_kernel(
    const u16* __restrict__ encb, const u16* __restrict__ wvT,
    const float* __restrict__ bv, const u16* __restrict__ wfb,
    const float* __restrict__ bf_g, const float* __restrict__ mask,
    const float* __restrict__ query_ws, const float* __restrict__ beta_ws,
    const float* __restrict__ kappa_out, float* __restrict__ score_out)
{
    // LDS: Ab [64 rows][8 chunks][8 u16] = 8192 B | Bb [128][8][8] = 16384 B
    // tT [64][136] u16 = 17408 B, union with Ab+Bb (24576 B total)
    __shared__ __align__(16) unsigned char smem[24576];
    u16* Ab = (u16*)smem;
    u16* Bb = (u16*)(smem + 8192);
    u16* tT = (u16*)smem;

    const int tid  = threadIdx.x;
    const int m0   = blockIdx.x * BM;
    const int b    = blockIdx.x >> 5;           // 32 m-tiles per batch
    const int lane = tid & 63;
    const int w    = tid >> 6;
    const int wr   = w >> 1, wc = w & 1;
    const int fr   = lane & 15, quad = lane >> 4;

    floatx4 acc2 = {};

    for (int nn = 0; nn < 8; ++nn) {
        const int n0 = nn * 128;

        // prefetch epilogue operands for this n-slice (L1-resident, overlaps GEMM)
        float qv[4];
        #pragma unroll
        for (int nt = 0; nt < 4; ++nt) {
            const int col = n0 + wc * 64 + nt * 16 + fr;
            qv[nt] = query_ws[(size_t)b * IHD + col] + bv[col];
        }
        bf16x8 wfr[4];
        #pragma unroll
        for (int ks = 0; ks < 4; ++ks)
            #pragma unroll
            for (int j = 0; j < 8; ++j)
                wfr[ks][j] = *(const __bf16*)&wfb[(n0 + ks * 32 + quad * 8 + j) * 8 + fr];

        floatx4 acc[2][4] = {};

        for (int kt = 0; kt < 8; ++kt) {
            const int ko = kt * BK;
            #pragma unroll
            for (int r = 0; r < 2; ++r) {        // A: 64 rows
                const int s  = r * 256 + tid;
                const int m  = s >> 3;
                const int cs = (s & 7) ^ (m & 7);
                async_cp16(Ab + (size_t)(r * 256 + (tid & 192)) * 8,
                           encb + (size_t)(m0 + m) * 512 + ko + cs * 8);
            }
            #pragma unroll
            for (int r = 0; r < 4; ++r) {        // B: 128 rows
                const int s  = r * 256 + tid;
                const int m  = s >> 3;
                const int cs = (s & 7) ^ (m & 7);
                async_cp16(Bb + (size_t)(r * 256 + (tid & 192)) * 8,
                           wvT + (size_t)(n0 + m) * 512 + ko + cs * 8);
            }
            __syncthreads();
            #pragma unroll
            for (int s2 = 0; s2 < 2; ++s2) {
                bf16x8 af[2], bfr[4];
                #pragma unroll
                for (int t = 0; t < 2; ++t) {
                    const int ma = wr * 32 + t * 16 + fr;
                    const int ca = (s2 * 4 + quad) ^ (ma & 7);
                    af[t] = *(const bf16x8*)&Ab[ma * 64 + ca * 8];
                }
                #pragma unroll
                for (int nt = 0; nt < 4; ++nt) {
                    const int nb = wc * 64 + nt * 16 + fr;
                    const int cb = (s2 * 4 + quad) ^ (nb & 7);
                    bfr[nt] = *(const bf16x8*)&Bb[nb * 64 + cb * 8];
                }
                #pragma unroll
                for (int mt = 0; mt < 2; ++mt)
                    #pragma unroll
                    for (int nt = 0; nt < 4; ++nt)
                        acc[mt][nt] = __builtin_amdgcn_mfma_f32_16x16x32_bf16(
                            af[mt], bfr[nt], acc[mt][nt], 0, 0, 0);
            }
            __syncthreads();
        }

        // ---- epilogue A: t = tanh(value + query + bv) -> tT (bf16)
        #pragma unroll
        for (int mt = 0; mt < 2; ++mt) {
            #pragma unroll
            for (int nt = 0; nt < 4; ++nt) {
                const int col = wc * 64 + nt * 16 + fr;
                #pragma unroll
                for (int reg = 0; reg < 4; ++reg) {
                    const int row = wr * 32 + mt * 16 + quad * 4 + reg;
                    ((__bf16*)tT)[row * 136 + col] =
                        (__bf16)tanh_fast(acc[mt][nt][reg] + qv[nt]);
                }
            }
        }
        __syncthreads();

        // ---- epilogue B: stage-2 MFMA  P += t(64x128) @ Wf_slice(128x8)
        #pragma unroll
        for (int ks = 0; ks < 4; ++ks) {
            const bf16x8 ta = *(const bf16x8*)&tT[(w * 16 + fr) * 136
                                                  + ks * 32 + quad * 8];
            acc2 = __builtin_amdgcn_mfma_f32_16x16x32_bf16(ta, wfr[ks], acc2, 0, 0, 0);
        }
        __syncthreads();   // protect tT before next n-iter staging
    }

    // ---- score: softplus(P + bf) * mask * exp(-beta*(kappa-u)^2)
    if (fr < NHEADS) {
        const float bfh = bf_g[fr];
        const float bet = beta_ws[b * NHEADS + fr];
        const float kap = kappa_out[b * NHEADS + fr];
        #pragma unroll
        for (int reg = 0; reg < 4; ++reg) {
            const int row = m0 + w * 16 + quad * 4 + reg;
            const int s = row & 2047;
            const float alpha = softplus_f(acc2[reg] + bfh) * mask[row];
            const float du = kap - (float)s;
            score_out[(size_t)row * NHEADS + fr] = alpha * __expf(-bet * du * du);
        }
    }
}

// ---------------------------------------------------------------------------
// context partials: part[sc][b][h][e] = sum_{s in chunk} score[b,s,h]*enc[b,s,e]
// grid (b=32, sc=16). Wave w owns heads {2w,2w+1} x all 512 e. No atomics.
// ---------------------------------------------------------------------------
__global__ __launch_bounds__(256) void context_kernel(
    const u16* __restrict__ encb, const float* __restrict__ score,
    float* __restrict__ ctx_part)
{
    __shared__ float s_sc[128 * NHEADS];
    const int b = blockIdx.x, sc = blockIdx.y, tid = threadIdx.x;
    const int lane = tid & 63, w = tid >> 6;
    const int e8 = lane * 8;
    const size_t srow0 = (size_t)b * SEQL + sc * 128;

    for (int i = tid; i < 128 * NHEADS; i += 256)
        s_sc[i] = score[srow0 * NHEADS + i];
    __syncthreads();

    float acc0[8] = {}, acc1[8] = {};
    const u16* ep = encb + srow0 * ENCD + e8;
    #pragma unroll 4
    for (int s = 0; s < 128; ++s) {
        const u16x8 ev = *(const u16x8*)(ep + (size_t)s * ENCD);
        const float2 sc2 = *(const float2*)&s_sc[s * NHEADS + 2 * w];
        #pragma unroll
        for (int j = 0; j < 8; ++j) {
            const float e = bf2f(ev[j]);
            acc0[j] = fmaf(sc2.x, e, acc0[j]);
            acc1[j] = fmaf(sc2.y, e, acc1[j]);
        }
    }

    float* outp = ctx_part + ((size_t)sc * BSZ + b) * (NHEADS * ENCD);
    *(float4*)&outp[(2 * w + 0) * ENCD + e8]     = make_float4(acc0[0], acc0[1], acc0[2], acc0[3]);
    *(float4*)&outp[(2 * w + 0) * ENCD + e8 + 4] = make_float4(acc0[4], acc0[5], acc0[6], acc0[7]);
    *(float4*)&outp[(2 * w + 1) * ENCD + e8]     = make_float4(acc1[0], acc1[1], acc1[2], acc1[3]);
    *(float4*)&outp[(2 * w + 1) * ENCD + e8 + 4] = make_float4(acc1[4], acc1[5], acc1[6], acc1[7]);
}

// ---------------------------------------------------------------------------
// ctx_ws[i] = sum_sc part[sc][i]   (i < 131072)
// ---------------------------------------------------------------------------
__global__ __launch_bounds__(256) void ctx_reduce_kernel(
    const float* __restrict__ part, float* __restrict__ ctx_ws)
{
    const int i = blockIdx.x * 256 + threadIdx.x;
    float a = 0.f;
    #pragma unroll
    for (int sc = 0; sc < 16; ++sc)
        a += part[(size_t)sc * 131072 + i];
    ctx_ws[i] = a;
}

// ---------------------------------------------------------------------------
// out_ctx[b,j] = ctx[b,:] @ Wfc[:,j] + bfc[j]
// ---------------------------------------------------------------------------
__global__ __launch_bounds__(256) void final_kernel(
    const float* __restrict__ ctx_ws, const float* __restrict__ Wfc,
    const float* __restrict__ bfc, float* __restrict__ out_ctx)
{
    __shared__ float s_ctx[32][128];
    const int jc = blockIdx.x, ks = blockIdx.y, tid = threadIdx.x;
    const int jl = tid & 31, bg = tid >> 5;
    const int j = jc * 32 + jl;
    float a0 = 0.f, a1 = 0.f, a2 = 0.f, a3 = 0.f;

    for (int t = 0; t < 4; ++t) {
        const int k0 = ks * 512 + t * 128;
        __syncthreads();
        for (int i = tid; i < 32 * 128; i += 256) {
            const int bb2 = i >> 7, kk = i & 127;
            s_ctx[bb2][kk] = ctx_ws[(size_t)bb2 * (NHEADS * ENCD) + k0 + kk];
        }
        __syncthreads();
        for (int kk = 0; kk < 128; ++kk) {
            const float wv = Wfc[(size_t)(k0 + kk) * ENCD + j];
            a0 = fmaf(s_ctx[bg * 4 + 0][kk], wv, a0);
            a1 = fmaf(s_ctx[bg * 4 + 1][kk], wv, a1);
            a2 = fmaf(s_ctx[bg * 4 + 2][kk], wv, a2);
            a3 = fmaf(s_ctx[bg * 4 + 3][kk], wv, a3);
        }
    }
    const float bias = (ks == 0) ? bfc[j] : 0.0f;
    atomicAdd(&out_ctx[(bg * 4 + 0) * ENCD + j], a0 + bias);
    atomicAdd(&out_ctx[(bg * 4 + 1) * ENCD + j], a1 + bias);
    atomicAdd(&out_ctx[(bg * 4 + 2) * ENCD + j], a2 + bias);
    atomicAdd(&out_ctx[(bg * 4 + 3) * ENCD + j], a3 + bias);
}

// ---------------------------------------------------------------------------
extern "C" void kernel_launch(void* const* d_in, const int* in_sizes, int n_in,
                              void* d_out, int out_size, void* d_ws, size_t ws_size,
                              hipStream_t stream)
{
    const float* enc   = (const float*)d_in[0];
    const float* dec   = (const float*)d_in[1];
    const float* kapin = (const float*)d_in[2];
    const float* mask  = (const float*)d_in[3];
    const float* Wv    = (const float*)d_in[4];
    const float* bv    = (const float*)d_in[5];
    const float* Wq    = (const float*)d_in[6];
    const float* bq    = (const float*)d_in[7];
    const float* Wf    = (const float*)d_in[8];
    const float* bf    = (const float*)d_in[9];
    const float* Wb    = (const float*)d_in[10];
    const float* bb    = (const float*)d_in[11];
    const float* Wk    = (const float*)d_in[12];
    const float* bk    = (const float*)d_in[13];
    const float* Wfc   = (const float*)d_in[14];
    const float* bfc   = (const float*)d_in[15];

    // outputs: context(32*512) | kappa(32*8) | score(32*2048*8)
    float* out       = (float*)d_out;
    float* out_ctx   = out;
    float* out_kappa = out + 16384;
    float* out_score = out + 16640;

    // workspace layout (bytes)
    char* w = (char*)d_ws;
    u16*   enc_bf   = (u16*)w;                     // 67108864 B
    float* ctx_part = (float*)(w + 67108864);      //  8388608 B
    u16*   wvT      = (u16*)(w + 75497472);        //  1048576 B
    float* q_ws     = (float*)(w + 76546048);      //   131072 B
    float* beta_ws  = (float*)(w + 76677120);      //     1024 B
    float* ctx_ws   = (float*)(w + 76678144);      //   524288 B
    u16*   wfb      = (u16*)(w + 77202432);        //    16400 B
                                                   // total 77218832 B

    hipMemsetAsync(out_ctx, 0, 16384 * sizeof(float), stream);

    conv_enc_kernel<<<dim3(16384), dim3(256), 0, stream>>>(enc, enc_bf);
    conv_w_kernel<<<dim3(129), dim3(256), 0, stream>>>(Wv, Wf, wvT, wfb);

    prep_kernel<<<dim3(BSZ, 33), dim3(256), 0, stream>>>(
        dec, kapin, Wq, bq, Wb, bb, Wk, bk, q_ws, beta_ws, out_kappa);

    gemm_score_kernel<<<dim3((BSZ * SEQL) / BM), dim3(256), 0, stream>>>(
        enc_bf, wvT, bv, wfb, bf, mask, q_ws, beta_ws, out_kappa, out_score);

    context_kernel<<<dim3(BSZ, 16), dim3(256), 0, stream>>>(
        enc_bf, out_score, ctx_part);

    ctx_reduce_kernel<<<dim3(512), dim3(256), 0, stream>>>(ctx_part, ctx_ws);

    final_kernel<<<dim3(16, 8), dim3(256), 0, stream>>>(
        ctx_ws, Wfc, bfc, out_ctx);
}